// Round 15
// baseline (173.241 us; speedup 1.0000x reference)
//
#include <hip/hip_runtime.h>

typedef __bf16 bf16x8 __attribute__((ext_vector_type(8)));
typedef __bf16 bf16x2 __attribute__((ext_vector_type(2)));
typedef float f32x4 __attribute__((ext_vector_type(4)));
typedef float f32x2 __attribute__((ext_vector_type(2)));
typedef unsigned short u16;
typedef unsigned int u32;

#define MFMA16(a, b, c) __builtin_amdgcn_mfma_f32_16x16x32_bf16((a), (b), (c), 0, 0, 0)

__device__ __forceinline__ u16 f2b(float f) {
  u32 u = __float_as_uint(f);
  u += 0x7FFFu + ((u >> 16) & 1u);
  return (u16)(u >> 16);
}
__device__ __forceinline__ float b2f(u16 h) { return __uint_as_float(((u32)h) << 16); }

__device__ __forceinline__ u32 pkbf(float a, float b) {
  bf16x2 h = {(__bf16)a, (__bf16)b};  // v_cvt_pk_bf16_f32
  return __builtin_bit_cast(u32, h);
}

__device__ __forceinline__ float max3f(float a, float b, float c) {
  float d;
  asm("v_max3_f32 %0, %1, %2, %3" : "=v"(d) : "v"(a), "v"(b), "v"(c));
  return d;
}

__device__ __forceinline__ float exp2_(float x) {
#if __has_builtin(__builtin_amdgcn_exp2f)
  return __builtin_amdgcn_exp2f(x);
#else
  return exp2f(x);
#endif
}

__device__ __forceinline__ void glds16(const void* g, void* l) {
  __builtin_amdgcn_global_load_lds((const __attribute__((address_space(1))) void*)g,
                                   (__attribute__((address_space(3))) void*)l, 16, 0, 0);
}

// ---------------- f32 -> bf16 conversion + RoPE table (fused) ----------------
__global__ __launch_bounds__(256) void cvt_k(const float* __restrict__ x,
                                             const float* __restrict__ wq,
                                             const float* __restrict__ wk,
                                             const float* __restrict__ wv,
                                             const float* __restrict__ wo,
                                             const int* __restrict__ pos,
                                             u16* __restrict__ dst,
                                             float2* __restrict__ tab) {
  size_t e = ((size_t)blockIdx.x * 256 + threadIdx.x) * 4;
  const float* src;
  size_t off;
  if (e < 8388608ull) {
    src = x; off = e;
  } else {
    size_t r = e - 8388608ull;
    u32 wi = (u32)(r >> 20);
    off = r & 1048575ull;
    src = (wi == 0) ? wq : (wi == 1) ? wk : (wi == 2) ? wv : wo;
  }
  float4 v = *(const float4*)(src + off);
  ushort4 o = make_ushort4(f2b(v.x), f2b(v.y), f2b(v.z), f2b(v.w));
  *(ushort4*)(dst + e) = o;
  if (blockIdx.x < 1024) {
    int i = blockIdx.x * 256 + threadIdx.x;
    int row = i >> 5, j = i & 31;
    float p = (float)pos[row];
    float inv = exp2f((float)j * -0.41524101186092029f);  // 10000^(-j/32)
    float s, c;
    sincosf(p * inv, &s, &c);
    tab[i] = make_float2(c, s);
  }
}

// ---------------- QKV projection GEMM: N-fused (C = X * [Wq;Wk;Wv]^T, 8192x3072) ----------------
// Block 128x256, 4 waves (2x2, wave-tile 64x128), BK=32, 3-slot counted ring (72KB LDS,
// 2 blocks/CU). reads/MFMA = 0.375 (vs 0.5 at 64x64); 32 MFMA per barrier interval.
// 768 blocks = 3 perfect rounds; mt-panels XCD-exclusive (X fetched once per XCD).
__global__ __launch_bounds__(256, 2) void gemm_qkv_k(const u16* __restrict__ Xb,
                                                     const u16* __restrict__ Wq,
                                                     const u16* __restrict__ Wk,
                                                     const u16* __restrict__ Wv,
                                                     const float2* __restrict__ tab,
                                                     u16* __restrict__ Qp,
                                                     u16* __restrict__ Kp,
                                                     u16* __restrict__ Vt) {
  __shared__ u16 As[3][8192];    // 128 rows x 32k, packed [64 rr][8 slot x 8elem]
  __shared__ u16 Bs[3][16384];   // 256 cols = 2 sub-structures of 128
  const int wgid = blockIdx.x;
  const int xcd = wgid & 7;
  const int idx = wgid >> 3;              // 0..95
  const int mt = xcd * 8 + idx / 12;      // 0..63 (XCD-exclusive X panels)
  const int nt = idx % 12;                // 0..11 (col-tile of 256 in fused 3072)
  const int z = nt >> 2;
  const int ntl = nt & 3;
  const u16* W = (z == 0) ? Wq : (z == 1) ? Wk : Wv;
  const int t = threadIdx.x;
  const int wave = t >> 6, lane = t & 63;
  const int lr = lane & 15, lg = lane >> 4;
  const int wr = wave >> 1, wc = wave & 1;  // 2x2 wave grid, wave-tile 64(M) x 128(N)

  // staging map (per 128-row sub-structure): thread t -> rr0=t>>3, slot s8=t&7 (pre-swizzled)
  const int rr0 = t >> 3;                 // 0..31
  const int s8 = t & 7;
  const int sl8 = s8 ^ (rr0 & 7);
  const int js = sl8 >> 2;                // row-half (0/1)
  const int kcs = sl8 & 3;                // k-chunk
  const u16* aS = Xb + (size_t)(mt * 128 + rr0 + 64 * js) * 1024 + kcs * 8;
  const u16* bS0 = W + (size_t)(ntl * 256 + rr0 + 64 * js) * 1024 + kcs * 8;
  const u16* bS1 = bS0 + 128 * 1024;      // second col-half sub-structure

  f32x4 acc[4][8];
#pragma unroll
  for (int i = 0; i < 4; ++i)
#pragma unroll
    for (int j = 0; j < 8; ++j) acc[i][j] = (f32x4){0.f, 0.f, 0.f, 0.f};

  // prologue: stage tiles 0,1 (6 glds each); drain tile 0 (keep tile 1 = 6)
#pragma unroll
  for (int tt = 0; tt < 2; ++tt) {
    const int kcol = tt * 32;
    glds16(aS + kcol, &As[tt][t * 8]);
    glds16(aS + 32 * 1024 + kcol, &As[tt][2048 + t * 8]);
    glds16(bS0 + kcol, &Bs[tt][t * 8]);
    glds16(bS0 + 32 * 1024 + kcol, &Bs[tt][2048 + t * 8]);
    glds16(bS1 + kcol, &Bs[tt][8192 + t * 8]);
    glds16(bS1 + 32 * 1024 + kcol, &Bs[tt][8192 + 2048 + t * 8]);
  }
  asm volatile("s_waitcnt vmcnt(6)" ::: "memory");
  __builtin_amdgcn_s_barrier();

  // read-side: A slot (wr*4+lg)^(lr&7); B sub wc, slots (lg)^(lr&7) and (4+lg)^(lr&7)
  const int arb = lr * 64 + (((wr << 2) + lg) ^ (lr & 7)) * 8;
  const int bbase = wc * 8192 + lr * 64;
  const int bs0 = (lg ^ (lr & 7)) * 8;
  const int bs1 = ((4 + lg) ^ (lr & 7)) * 8;

  int sl = 0, sp2 = 2;
  for (int tau = 0; tau < 32; ++tau) {
    const u16* Asl = &As[sl][0];
    const u16* Bsl = &Bs[sl][0];
    bf16x8 af[4], bf[8];
#pragma unroll
    for (int mi = 0; mi < 4; ++mi) af[mi] = *(const bf16x8*)&Asl[arb + mi * 1024];
#pragma unroll
    for (int nj = 0; nj < 4; ++nj) {
      bf[nj] = *(const bf16x8*)&Bsl[bbase + nj * 1024 + bs0];
      bf[nj + 4] = *(const bf16x8*)&Bsl[bbase + nj * 1024 + bs1];
    }
    if (tau < 30) {
      u16* Ad = &As[sp2][0];
      u16* Bd = &Bs[sp2][0];
      const int kcol = (tau + 2) * 32;
      glds16(aS + kcol, &Ad[t * 8]);
      glds16(aS + 32 * 1024 + kcol, &Ad[2048 + t * 8]);
      glds16(bS0 + kcol, &Bd[t * 8]);
      glds16(bS0 + 32 * 1024 + kcol, &Bd[2048 + t * 8]);
      glds16(bS1 + kcol, &Bd[8192 + t * 8]);
      glds16(bS1 + 32 * 1024 + kcol, &Bd[8192 + 2048 + t * 8]);
    }
#pragma unroll
    for (int mi = 0; mi < 4; ++mi)
#pragma unroll
      for (int nj = 0; nj < 8; ++nj)
        acc[mi][nj] = MFMA16(af[mi], bf[nj], acc[mi][nj]);
    if (tau < 30) asm volatile("s_waitcnt vmcnt(6)" ::: "memory");
    else asm volatile("s_waitcnt vmcnt(0)" ::: "memory");
    __builtin_amdgcn_s_barrier();
    sl = (sl == 2) ? 0 : sl + 1;
    sp2 = (sp2 == 2) ? 0 : sp2 + 1;
  }

  // epilogue: block's 256 cols are within one z (256 | 1024)
  const int rbase = mt * 128 + wr * 64 + lg * 4;
  const int cbase = ntl * 256 + wc * 128 + lr;  // col within z's 1024
  if (z < 2) {
    u16* out = (z == 0) ? Qp : Kp;
    const float scl = (z == 0) ? 0.18033688011112043f : 1.0f;  // 0.125*log2(e) for Q
#pragma unroll
    for (int mi = 0; mi < 4; ++mi)
#pragma unroll
      for (int nj = 0; nj < 8; ++nj) {
        int row0 = rbase + mi * 16;
        int col = cbase + nj * 16;
        int j = (col >> 1) & 31;
        float sgn = (col & 1) ? 1.f : -1.f;
#pragma unroll
        for (int r = 0; r < 4; ++r) {
          float self = acc[mi][nj][r];
          float partner = __shfl_xor(self, 1);
          float2 cs = tab[(size_t)(row0 + r) * 32 + j];
          float o = (self * cs.x + partner * cs.y * sgn) * scl;
          out[(size_t)(row0 + r) * 1024 + col] = f2b(o);
        }
      }
  } else {
#pragma unroll
    for (int mi = 0; mi < 4; ++mi)
#pragma unroll
      for (int nj = 0; nj < 8; ++nj) {
        int row0 = rbase + mi * 16;
        int e = cbase + nj * 16;
        int b = row0 >> 11, s = row0 & 2047;
        ushort4 pk = make_ushort4(f2b(acc[mi][nj][0]), f2b(acc[mi][nj][1]),
                                  f2b(acc[mi][nj][2]), f2b(acc[mi][nj][3]));
        *(ushort4*)&Vt[((size_t)(b * 1024 + e)) * 2048 + s] = pk;
      }
  }
}

// ---------------- causal flash attention: 8 waves x 16 q-rows, 128 q/block, 1024 blocks ----------------
__global__ __launch_bounds__(512, 6) void fattn_k(const u16* __restrict__ Qp,
                                                  const u16* __restrict__ Kp,
                                                  const u16* __restrict__ Vt,
                                                  u16* __restrict__ Ao) {
  __shared__ u16 Ks[2][64 * 64];    // [buf][kv][d], swizzled (16KB)
  __shared__ u16 Vs[2][64 * 64];    // [buf][d][kv], swizzled (16KB)
  __shared__ u16 Ps[8][16 * 64];    // per-wave [q16][kv64], swizzled (16KB)
  const int blk = blockIdx.x;
  const int g = blk & 7, jj = blk >> 3;     // 1024 blocks, jj 0..127
  const int bh = g * 8 + (jj & 7);          // xcd g owns bh [8g, 8g+8)
  const int qt = 15 - (jj >> 3);            // long blocks first (qt 15..0)
  const int b = bh >> 4, h = bh & 15;
  const int tid = threadIdx.x, wave = tid >> 6, lane = tid & 63;
  const int lr = lane & 15, lg = lane >> 4;
  const int q0w = qt * 128 + wave * 16;

  bf16x8 qf0, qf1;
  {
    const u16* qb = Qp + ((size_t)(b * 2048 + q0w + lr)) * 1024 + h * 64 + lg * 8;
    qf0 = *(const bf16x8*)qb;
    qf1 = *(const bf16x8*)(qb + 32);
  }

  float m = -1e30f, l = 0.f;
  f32x4 oacc[4];
#pragma unroll
  for (int d4 = 0; d4 < 4; ++d4) oacc[d4] = (f32x4){0.f, 0.f, 0.f, 0.f};
  const f32x4 fz = {0.f, 0.f, 0.f, 0.f};

  const int srow = lane >> 3;
  const int schunk = (lane & 7) ^ srow;
  const u16* kbase = Kp + ((size_t)(b * 2048 + 8 * wave + srow)) * 1024 + h * 64 + schunk * 8;
  const u16* vbase = Vt + ((size_t)(b * 1024 + h * 64 + 8 * wave + srow)) * 2048 + schunk * 8;
  char* psbase = (char*)&Ps[wave][0];

  const int ktmax = 2 * qt + 1;
  const int ktneed = 2 * qt + (wave >> 2);

  glds16(kbase, &Ks[0][(8 * wave) * 64]);
  glds16(vbase, &Vs[0][(8 * wave) * 64]);

  int cur = 0;
  for (int kt = 0; kt <= ktmax; ++kt, cur ^= 1) {
    __syncthreads();
    if (kt < ktmax) {
      const int nx = cur ^ 1, k1 = kt + 1;
      glds16(kbase + (size_t)k1 * 65536, &Ks[nx][(8 * wave) * 64]);
      glds16(vbase + k1 * 64, &Vs[nx][(8 * wave) * 64]);
    }
    if (kt > ktneed) continue;
    const u16* KB = &Ks[cur][0];
    const u16* VB = &Vs[cur][0];

    f32x4 sc[4];
#pragma unroll
    for (int ks = 0; ks < 4; ++ks) {
      const int krow = ks * 16 + lr;
      const int swk = lr & 7;
      bf16x8 kf0 = *(const bf16x8*)&KB[krow * 64 + ((lg ^ swk) * 8)];
      bf16x8 kf1 = *(const bf16x8*)&KB[krow * 64 + (((lg + 4) ^ swk) * 8)];
      f32x4 s = MFMA16(kf0, qf0, fz);
      s = MFMA16(kf1, qf1, s);
      sc[ks] = s;
    }
    if (kt == ktneed) {  // causal mask (diagonal tile only)
      int q = q0w + lr;
#pragma unroll
      for (int ks = 0; ks < 4; ++ks)
#pragma unroll
        for (int r = 0; r < 4; ++r) {
          int kv = kt * 64 + ks * 16 + lg * 4 + r;
          if (kv > q) sc[ks][r] = -__builtin_inff();
        }
    }

    {
      float t0 = max3f(sc[0][0], sc[0][1], sc[0][2]);
      float t1 = max3f(sc[0][3], sc[1][0], sc[1][1]);
      float t2 = max3f(sc[1][2], sc[1][3], sc[2][0]);
      float t3 = max3f(sc[2][1], sc[2][2], sc[2][3]);
      float t4 = max3f(sc[3][0], sc[3][1], sc[3][2]);
      float pm = max3f(max3f(t0, t1, t2), max3f(t3, t4, sc[3][3]), -1e30f);
      pm = fmaxf(pm, __shfl_xor(pm, 16));
      pm = fmaxf(pm, __shfl_xor(pm, 32));
      if (__any(pm > m + 8.f)) {
        float mn = fmaxf(m, pm);
        float corr = exp2_(m - mn);
        m = mn;
        l *= corr;
        float cb[4];
#pragma unroll
        for (int r = 0; r < 4; ++r) cb[r] = __shfl(corr, (lane & 48) | (lg * 4 + r));
#pragma unroll
        for (int d4 = 0; d4 < 4; ++d4)
#pragma unroll
          for (int r = 0; r < 4; ++r) oacc[d4][r] *= cb[r];
      }
      const f32x2 ms = {m, m};
      f32x2 rs2 = {0.f, 0.f};
#pragma unroll
      for (int ks = 0; ks < 4; ++ks) {
        f32x2 lo = {sc[ks][0], sc[ks][1]};
        f32x2 hi = {sc[ks][2], sc[ks][3]};
        lo = lo - ms;
        hi = hi - ms;
        lo[0] = exp2_(lo[0]); lo[1] = exp2_(lo[1]);
        hi[0] = exp2_(hi[0]); hi[1] = exp2_(hi[1]);
        rs2 += lo;
        rs2 += hi;
        sc[ks][0] = lo[0]; sc[ks][1] = lo[1];
        sc[ks][2] = hi[0]; sc[ks][3] = hi[1];
      }
      float rs = rs2[0] + rs2[1];
      rs += __shfl_xor(rs, 16);
      rs += __shfl_xor(rs, 32);
      l += rs;
    }

    bf16x8 pa0, pa1;
    {
      const int swp = lr & 7;
#pragma unroll
      for (int ks = 0; ks < 4; ++ks) {
        const int chunk = (2 * ks + (lg >> 1)) ^ swp;
        char* p = psbase + lr * 128 + chunk * 16 + (lg & 1) * 8;
        *(uint2*)p = make_uint2(pkbf(sc[ks][0], sc[ks][1]),
                                pkbf(sc[ks][2], sc[ks][3]));
      }
      pa0 = *(const bf16x8*)(psbase + lr * 128 + ((lg ^ swp) * 16));
      pa1 = *(const bf16x8*)(psbase + lr * 128 + (((lg + 4) ^ swp) * 16));
    }
#pragma unroll
    for (int d4 = 0; d4 < 4; ++d4) {
      const int vrow = d4 * 16 + lr;
      const int swv = lr & 7;
      bf16x8 vf0 = *(const bf16x8*)&VB[vrow * 64 + ((lg ^ swv) * 8)];
      bf16x8 vf1 = *(const bf16x8*)&VB[vrow * 64 + (((lg + 4) ^ swv) * 8)];
      oacc[d4] = MFMA16(pa0, vf0, oacc[d4]);
      oacc[d4] = MFMA16(pa1, vf1, oacc[d4]);
    }
  }

  {
    float lb[4];
#pragma unroll
    for (int r = 0; r < 4; ++r) lb[r] = __shfl(l, (lane & 48) | (lg * 4 + r));
#pragma unroll
    for (int r = 0; r < 4; ++r) {
      float inv = 1.f / lb[r];
      int q = q0w + lg * 4 + r;
      u16* orow = Ao + ((size_t)(b * 2048 + q)) * 1024 + h * 64 + lr;
#pragma unroll
      for (int d4 = 0; d4 < 4; ++d4) orow[d4 * 16] = f2b(oacc[d4][r] * inv);
    }
  }
}

// ---------------- output projection: 128x128 tile, BK=32, 3-slot counted ring, f32 out ----------------
__global__ __launch_bounds__(256, 3) void gemm_wo_k(const u16* __restrict__ Ab,
                                                    const u16* __restrict__ Wo,
                                                    float* __restrict__ Out) {
  __shared__ u16 As[3][4096];
  __shared__ u16 Bs[3][4096];
  const int wgid = blockIdx.x;
  const int xcd = wgid & 7;
  const int idx = wgid >> 3;             // 0..63
  const int mt = xcd * 8 + (idx >> 3);   // 0..63
  const int nt = idx & 7;
  const int t = threadIdx.x;
  const int wave = t >> 6, lane = t & 63;
  const int lr = lane & 15, lg = lane >> 4;
  const int wr = wave >> 1, wc = wave & 1;

  const int rr0 = t >> 3;
  const int s8 = t & 7;
  const int sl8 = s8 ^ (rr0 & 7);
  const int js = sl8 >> 2;
  const int kcs = sl8 & 3;
  const u16* aS = Ab + (size_t)(mt * 128 + rr0 + 64 * js) * 1024 + kcs * 8;
  const u16* bS = Wo + (size_t)(nt * 128 + rr0 + 64 * js) * 1024 + kcs * 8;

  f32x4 acc[4][4];
#pragma unroll
  for (int i = 0; i < 4; ++i)
#pragma unroll
    for (int j = 0; j < 4; ++j) acc[i][j] = (f32x4){0.f, 0.f, 0.f, 0.f};

#pragma unroll
  for (int tt = 0; tt < 2; ++tt) {
    const int kcol = tt * 32;
    glds16(aS + kcol, &As[tt][t * 8]);
    glds16(aS + 32 * 1024 + kcol, &As[tt][2048 + t * 8]);
    glds16(bS + kcol, &Bs[tt][t * 8]);
    glds16(bS + 32 * 1024 + kcol, &Bs[tt][2048 + t * 8]);
  }
  asm volatile("s_waitcnt vmcnt(4)" ::: "memory");
  __builtin_amdgcn_s_barrier();

  const int arb = lr * 64 + (((wr << 2) + lg) ^ (lr & 7)) * 8;
  const int brb = lr * 64 + (((wc << 2) + lg) ^ (lr & 7)) * 8;

  int sl = 0, sp2 = 2;
  for (int tau = 0; tau < 32; ++tau) {
    const u16* Asl = &As[sl][0];
    const u16* Bsl = &Bs[sl][0];
    bf16x8 af[4], bf[4];
#pragma unroll
    for (int mi = 0; mi < 4; ++mi) af[mi] = *(const bf16x8*)&Asl[arb + mi * 1024];
#pragma unroll
    for (int nj = 0; nj < 4; ++nj) bf[nj] = *(const bf16x8*)&Bsl[brb + nj * 1024];
    if (tau < 30) {
      u16* Ad = &As[sp2][0];
      u16* Bd = &Bs[sp2][0];
      const int kcol = (tau + 2) * 32;
      glds16(aS + kcol, &Ad[t * 8]);
      glds16(aS + 32 * 1024 + kcol, &Ad[2048 + t * 8]);
      glds16(bS + kcol, &Bd[t * 8]);
      glds16(bS + 32 * 1024 + kcol, &Bd[2048 + t * 8]);
    }
#pragma unroll
    for (int mi = 0; mi < 4; ++mi)
#pragma unroll
      for (int nj = 0; nj < 4; ++nj)
        acc[mi][nj] = MFMA16(af[mi], bf[nj], acc[mi][nj]);
    if (tau < 30) asm volatile("s_waitcnt vmcnt(4)" ::: "memory");
    else asm volatile("s_waitcnt vmcnt(0)" ::: "memory");
    __builtin_amdgcn_s_barrier();
    sl = (sl == 2) ? 0 : sl + 1;
    sp2 = (sp2 == 2) ? 0 : sp2 + 1;
  }

  const int rbase = mt * 128 + wr * 64 + lg * 4;
  const int cbase = nt * 128 + wc * 64 + lr;
#pragma unroll
  for (int mi = 0; mi < 4; ++mi)
#pragma unroll
    for (int nj = 0; nj < 4; ++nj) {
      int row0 = rbase + mi * 16;
      int col = cbase + nj * 16;
#pragma unroll
      for (int r = 0; r < 4; ++r)
        Out[(size_t)(row0 + r) * 1024 + col] = acc[mi][nj][r];
    }
}

extern "C" void kernel_launch(void* const* d_in, const int* in_sizes, int n_in,
                              void* d_out, int out_size, void* d_ws, size_t ws_size,
                              hipStream_t stream) {
  const float* x = (const float*)d_in[0];
  const int* pos = (const int*)d_in[1];
  const float* wq = (const float*)d_in[2];
  const float* wk = (const float*)d_in[3];
  const float* wv = (const float*)d_in[4];
  const float* wo = (const float*)d_in[5];

  char* ws = (char*)d_ws;
  u16* xb = (u16*)ws;
  u16* wqb = xb + 8388608;
  u16* wkb = wqb + 1048576;
  u16* wvb = wkb + 1048576;
  u16* wob = wvb + 1048576;
  float2* tab = (float2*)(ws + 25165824);
  u16* Qp = (u16*)(ws + 27262976);
  u16* Kp = (u16*)(ws + 27262976 + 16777216);
  u16* Vt = (u16*)(ws + 27262976 + 2 * 16777216);
  u16* Ao = (u16*)(ws + 27262976 + 3 * 16777216);

  hipLaunchKernelGGL(cvt_k, dim3(12288), dim3(256), 0, stream, x, wq, wk, wv, wo, pos,
                     xb, tab);
  hipLaunchKernelGGL(gemm_qkv_k, dim3(768), dim3(256), 0, stream, xb, wqb, wkb, wvb,
                     tab, Qp, Kp, Vt);
  hipLaunchKernelGGL(fattn_k, dim3(1024), dim3(512), 0, stream, Qp, Kp, Vt, Ao);
  hipLaunchKernelGGL(gemm_wo_k, dim3(512), dim3(256), 0, stream, Ao, wob, (float*)d_out);
}

// Round 16
// 161.902 us; speedup vs baseline: 1.0700x; 1.0700x over previous
//
#include <hip/hip_runtime.h>

typedef __bf16 bf16x8 __attribute__((ext_vector_type(8)));
typedef __bf16 bf16x2 __attribute__((ext_vector_type(2)));
typedef float f32x4 __attribute__((ext_vector_type(4)));
typedef float f32x2 __attribute__((ext_vector_type(2)));
typedef unsigned short u16;
typedef unsigned int u32;

#define MFMA16(a, b, c) __builtin_amdgcn_mfma_f32_16x16x32_bf16((a), (b), (c), 0, 0, 0)

__device__ __forceinline__ u16 f2b(float f) {
  u32 u = __float_as_uint(f);
  u += 0x7FFFu + ((u >> 16) & 1u);
  return (u16)(u >> 16);
}
__device__ __forceinline__ float b2f(u16 h) { return __uint_as_float(((u32)h) << 16); }

__device__ __forceinline__ u32 pkbf(float a, float b) {
  bf16x2 h = {(__bf16)a, (__bf16)b};  // v_cvt_pk_bf16_f32
  return __builtin_bit_cast(u32, h);
}

__device__ __forceinline__ float max3f(float a, float b, float c) {
  float d;
  asm("v_max3_f32 %0, %1, %2, %3" : "=v"(d) : "v"(a), "v"(b), "v"(c));
  return d;
}

__device__ __forceinline__ float exp2_(float x) {
#if __has_builtin(__builtin_amdgcn_exp2f)
  return __builtin_amdgcn_exp2f(x);
#else
  return exp2f(x);
#endif
}

__device__ __forceinline__ void glds16(const void* g, void* l) {
  __builtin_amdgcn_global_load_lds((const __attribute__((address_space(1))) void*)g,
                                   (__attribute__((address_space(3))) void*)l, 16, 0, 0);
}

// ---------------- f32 -> bf16 conversion + RoPE table (fused) ----------------
__global__ __launch_bounds__(256) void cvt_k(const float* __restrict__ x,
                                             const float* __restrict__ wq,
                                             const float* __restrict__ wk,
                                             const float* __restrict__ wv,
                                             const float* __restrict__ wo,
                                             const int* __restrict__ pos,
                                             u16* __restrict__ dst,
                                             float2* __restrict__ tab) {
  size_t e = ((size_t)blockIdx.x * 256 + threadIdx.x) * 4;
  const float* src;
  size_t off;
  if (e < 8388608ull) {
    src = x; off = e;
  } else {
    size_t r = e - 8388608ull;
    u32 wi = (u32)(r >> 20);
    off = r & 1048575ull;
    src = (wi == 0) ? wq : (wi == 1) ? wk : (wi == 2) ? wv : wo;
  }
  float4 v = *(const float4*)(src + off);
  ushort4 o = make_ushort4(f2b(v.x), f2b(v.y), f2b(v.z), f2b(v.w));
  *(ushort4*)(dst + e) = o;
  if (blockIdx.x < 1024) {
    int i = blockIdx.x * 256 + threadIdx.x;
    int row = i >> 5, j = i & 31;
    float p = (float)pos[row];
    float inv = exp2f((float)j * -0.41524101186092029f);  // 10000^(-j/32)
    float s, c;
    sincosf(p * inv, &s, &c);
    tab[i] = make_float2(c, s);
  }
}

// ---------------- QKV projection GEMM: 128x128 tile, BK=32, 3-slot counted ring ----------------
// R13/R14-best: 48KB LDS -> 3 blocks/CU; 1536 blocks = 2 perfect rounds; pin-less K-loop.
__global__ __launch_bounds__(256, 3) void gemm_qkv_k(const u16* __restrict__ Xb,
                                                     const u16* __restrict__ Wq,
                                                     const u16* __restrict__ Wk,
                                                     const u16* __restrict__ Wv,
                                                     const float2* __restrict__ tab,
                                                     u16* __restrict__ Qp,
                                                     u16* __restrict__ Kp,
                                                     u16* __restrict__ Vt) {
  __shared__ u16 As[3][4096];  // 8KB per slot
  __shared__ u16 Bs[3][4096];
  const int wgid = blockIdx.x;
  const int xcd = wgid & 7;
  const int idx = wgid >> 3;              // 0..191
  const int P = xcd * 24 + (idx >> 3);    // 0..191 panels (z-major)
  const int nt = idx & 7;
  const int z = P >> 6;
  const int mt = P & 63;
  const u16* W = (z == 0) ? Wq : (z == 1) ? Wk : Wv;
  const int t = threadIdx.x;
  const int wave = t >> 6, lane = t & 63;
  const int lr = lane & 15, lg = lane >> 4;
  const int wr = wave >> 1, wc = wave & 1;  // 2x2 wave grid, wave-tile 64x64

  const int rr0 = t >> 3;                 // 0..31
  const int s8 = t & 7;
  const int sl8 = s8 ^ (rr0 & 7);
  const int js = sl8 >> 2;                // row-half
  const int kcs = sl8 & 3;                // k-chunk
  const u16* aS = Xb + (size_t)(mt * 128 + rr0 + 64 * js) * 1024 + kcs * 8;
  const u16* bS = W + (size_t)(nt * 128 + rr0 + 64 * js) * 1024 + kcs * 8;

  f32x4 acc[4][4];
#pragma unroll
  for (int i = 0; i < 4; ++i)
#pragma unroll
    for (int j = 0; j < 4; ++j) acc[i][j] = (f32x4){0.f, 0.f, 0.f, 0.f};

#pragma unroll
  for (int tt = 0; tt < 2; ++tt) {
    const int kcol = tt * 32;
    glds16(aS + kcol, &As[tt][t * 8]);
    glds16(aS + 32 * 1024 + kcol, &As[tt][2048 + t * 8]);
    glds16(bS + kcol, &Bs[tt][t * 8]);
    glds16(bS + 32 * 1024 + kcol, &Bs[tt][2048 + t * 8]);
  }
  asm volatile("s_waitcnt vmcnt(4)" ::: "memory");
  __builtin_amdgcn_s_barrier();

  const int arb = lr * 64 + (((wr << 2) + lg) ^ (lr & 7)) * 8;
  const int brb = lr * 64 + (((wc << 2) + lg) ^ (lr & 7)) * 8;

  int sl = 0, sp2 = 2;
  for (int tau = 0; tau < 32; ++tau) {
    const u16* Asl = &As[sl][0];
    const u16* Bsl = &Bs[sl][0];
    bf16x8 af[4], bf[4];
#pragma unroll
    for (int mi = 0; mi < 4; ++mi) af[mi] = *(const bf16x8*)&Asl[arb + mi * 1024];
#pragma unroll
    for (int nj = 0; nj < 4; ++nj) bf[nj] = *(const bf16x8*)&Bsl[brb + nj * 1024];
    if (tau < 30) {
      u16* Ad = &As[sp2][0];
      u16* Bd = &Bs[sp2][0];
      const int kcol = (tau + 2) * 32;
      glds16(aS + kcol, &Ad[t * 8]);
      glds16(aS + 32 * 1024 + kcol, &Ad[2048 + t * 8]);
      glds16(bS + kcol, &Bd[t * 8]);
      glds16(bS + 32 * 1024 + kcol, &Bd[2048 + t * 8]);
    }
    // compiler-scheduled ds_read->MFMA interleave; reads retire before end barrier.
#pragma unroll
    for (int mi = 0; mi < 4; ++mi)
#pragma unroll
      for (int nj = 0; nj < 4; ++nj)
        acc[mi][nj] = MFMA16(af[mi], bf[nj], acc[mi][nj]);
    if (tau < 30) asm volatile("s_waitcnt vmcnt(4)" ::: "memory");
    else asm volatile("s_waitcnt vmcnt(0)" ::: "memory");
    __builtin_amdgcn_s_barrier();
    sl = (sl == 2) ? 0 : sl + 1;
    sp2 = (sp2 == 2) ? 0 : sp2 + 1;
  }

  const int rbase = mt * 128 + wr * 64 + lg * 4;
  const int cbase = nt * 128 + wc * 64 + lr;
  if (z < 2) {
    u16* out = (z == 0) ? Qp : Kp;
    const float scl = (z == 0) ? 0.18033688011112043f : 1.0f;  // 0.125*log2(e) for Q
#pragma unroll
    for (int mi = 0; mi < 4; ++mi)
#pragma unroll
      for (int nj = 0; nj < 4; ++nj) {
        int row0 = rbase + mi * 16;
        int col = cbase + nj * 16;
        int j = (col >> 1) & 31;
        float sgn = (col & 1) ? 1.f : -1.f;
#pragma unroll
        for (int r = 0; r < 4; ++r) {
          float self = acc[mi][nj][r];
          float partner = __shfl_xor(self, 1);
          float2 cs = tab[(size_t)(row0 + r) * 32 + j];
          float o = (self * cs.x + partner * cs.y * sgn) * scl;
          out[(size_t)(row0 + r) * 1024 + col] = f2b(o);
        }
      }
  } else {
#pragma unroll
    for (int mi = 0; mi < 4; ++mi)
#pragma unroll
      for (int nj = 0; nj < 4; ++nj) {
        int row0 = rbase + mi * 16;
        int e = cbase + nj * 16;
        int b = row0 >> 11, s = row0 & 2047;
        ushort4 pk = make_ushort4(f2b(acc[mi][nj][0]), f2b(acc[mi][nj][1]),
                                  f2b(acc[mi][nj][2]), f2b(acc[mi][nj][3]));
        *(ushort4*)&Vt[((size_t)(b * 1024 + e)) * 2048 + s] = pk;
      }
  }
}

// ---------------- causal flash attention: 8 waves x 16 q-rows, 128 q/block, 1024 blocks ----------------
__global__ __launch_bounds__(512, 6) void fattn_k(const u16* __restrict__ Qp,
                                                  const u16* __restrict__ Kp,
                                                  const u16* __restrict__ Vt,
                                                  u16* __restrict__ Ao) {
  __shared__ u16 Ks[2][64 * 64];    // [buf][kv][d], swizzled (16KB)
  __shared__ u16 Vs[2][64 * 64];    // [buf][d][kv], swizzled (16KB)
  __shared__ u16 Ps[8][16 * 64];    // per-wave [q16][kv64], swizzled (16KB)
  const int blk = blockIdx.x;
  const int g = blk & 7, jj = blk >> 3;     // 1024 blocks, jj 0..127
  const int bh = g * 8 + (jj & 7);          // xcd g owns bh [8g, 8g+8)
  const int qt = 15 - (jj >> 3);            // long blocks first (qt 15..0)
  const int b = bh >> 4, h = bh & 15;
  const int tid = threadIdx.x, wave = tid >> 6, lane = tid & 63;
  const int lr = lane & 15, lg = lane >> 4;
  const int q0w = qt * 128 + wave * 16;

  bf16x8 qf0, qf1;
  {
    const u16* qb = Qp + ((size_t)(b * 2048 + q0w + lr)) * 1024 + h * 64 + lg * 8;
    qf0 = *(const bf16x8*)qb;
    qf1 = *(const bf16x8*)(qb + 32);
  }

  float m = -1e30f, l = 0.f;
  f32x4 oacc[4];
#pragma unroll
  for (int d4 = 0; d4 < 4; ++d4) oacc[d4] = (f32x4){0.f, 0.f, 0.f, 0.f};
  const f32x4 fz = {0.f, 0.f, 0.f, 0.f};

  const int srow = lane >> 3;
  const int schunk = (lane & 7) ^ srow;
  const u16* kbase = Kp + ((size_t)(b * 2048 + 8 * wave + srow)) * 1024 + h * 64 + schunk * 8;
  const u16* vbase = Vt + ((size_t)(b * 1024 + h * 64 + 8 * wave + srow)) * 2048 + schunk * 8;
  char* psbase = (char*)&Ps[wave][0];

  const int ktmax = 2 * qt + 1;
  const int ktneed = 2 * qt + (wave >> 2);

  glds16(kbase, &Ks[0][(8 * wave) * 64]);
  glds16(vbase, &Vs[0][(8 * wave) * 64]);

  int cur = 0;
  for (int kt = 0; kt <= ktmax; ++kt, cur ^= 1) {
    __syncthreads();
    if (kt < ktmax) {
      const int nx = cur ^ 1, k1 = kt + 1;
      glds16(kbase + (size_t)k1 * 65536, &Ks[nx][(8 * wave) * 64]);
      glds16(vbase + k1 * 64, &Vs[nx][(8 * wave) * 64]);
    }
    if (kt > ktneed) continue;
    const u16* KB = &Ks[cur][0];
    const u16* VB = &Vs[cur][0];

    f32x4 sc[4];
#pragma unroll
    for (int ks = 0; ks < 4; ++ks) {
      const int krow = ks * 16 + lr;
      const int swk = lr & 7;
      bf16x8 kf0 = *(const bf16x8*)&KB[krow * 64 + ((lg ^ swk) * 8)];
      bf16x8 kf1 = *(const bf16x8*)&KB[krow * 64 + (((lg + 4) ^ swk) * 8)];
      f32x4 s = MFMA16(kf0, qf0, fz);
      s = MFMA16(kf1, qf1, s);
      sc[ks] = s;
    }
    if (kt == ktneed) {  // causal mask (diagonal tile only)
      int q = q0w + lr;
#pragma unroll
      for (int ks = 0; ks < 4; ++ks)
#pragma unroll
        for (int r = 0; r < 4; ++r) {
          int kv = kt * 64 + ks * 16 + lg * 4 + r;
          if (kv > q) sc[ks][r] = -__builtin_inff();
        }
    }

    {
      float t0 = max3f(sc[0][0], sc[0][1], sc[0][2]);
      float t1 = max3f(sc[0][3], sc[1][0], sc[1][1]);
      float t2 = max3f(sc[1][2], sc[1][3], sc[2][0]);
      float t3 = max3f(sc[2][1], sc[2][2], sc[2][3]);
      float t4 = max3f(sc[3][0], sc[3][1], sc[3][2]);
      float pm = max3f(max3f(t0, t1, t2), max3f(t3, t4, sc[3][3]), -1e30f);
      pm = fmaxf(pm, __shfl_xor(pm, 16));
      pm = fmaxf(pm, __shfl_xor(pm, 32));
      if (__any(pm > m + 8.f)) {
        float mn = fmaxf(m, pm);
        float corr = exp2_(m - mn);
        m = mn;
        l *= corr;
        float cb[4];
#pragma unroll
        for (int r = 0; r < 4; ++r) cb[r] = __shfl(corr, (lane & 48) | (lg * 4 + r));
#pragma unroll
        for (int d4 = 0; d4 < 4; ++d4)
#pragma unroll
          for (int r = 0; r < 4; ++r) oacc[d4][r] *= cb[r];
      }
      const f32x2 ms = {m, m};
      f32x2 rs2 = {0.f, 0.f};
#pragma unroll
      for (int ks = 0; ks < 4; ++ks) {
        f32x2 lo = {sc[ks][0], sc[ks][1]};
        f32x2 hi = {sc[ks][2], sc[ks][3]};
        lo = lo - ms;
        hi = hi - ms;
        lo[0] = exp2_(lo[0]); lo[1] = exp2_(lo[1]);
        hi[0] = exp2_(hi[0]); hi[1] = exp2_(hi[1]);
        rs2 += lo;
        rs2 += hi;
        sc[ks][0] = lo[0]; sc[ks][1] = lo[1];
        sc[ks][2] = hi[0]; sc[ks][3] = hi[1];
      }
      float rs = rs2[0] + rs2[1];
      rs += __shfl_xor(rs, 16);
      rs += __shfl_xor(rs, 32);
      l += rs;
    }

    bf16x8 pa0, pa1;
    {
      const int swp = lr & 7;
#pragma unroll
      for (int ks = 0; ks < 4; ++ks) {
        const int chunk = (2 * ks + (lg >> 1)) ^ swp;
        char* p = psbase + lr * 128 + chunk * 16 + (lg & 1) * 8;
        *(uint2*)p = make_uint2(pkbf(sc[ks][0], sc[ks][1]),
                                pkbf(sc[ks][2], sc[ks][3]));
      }
      pa0 = *(const bf16x8*)(psbase + lr * 128 + ((lg ^ swp) * 16));
      pa1 = *(const bf16x8*)(psbase + lr * 128 + (((lg + 4) ^ swp) * 16));
    }
#pragma unroll
    for (int d4 = 0; d4 < 4; ++d4) {
      const int vrow = d4 * 16 + lr;
      const int swv = lr & 7;
      bf16x8 vf0 = *(const bf16x8*)&VB[vrow * 64 + ((lg ^ swv) * 8)];
      bf16x8 vf1 = *(const bf16x8*)&VB[vrow * 64 + (((lg + 4) ^ swv) * 8)];
      oacc[d4] = MFMA16(pa0, vf0, oacc[d4]);
      oacc[d4] = MFMA16(pa1, vf1, oacc[d4]);
    }
  }

  {
    float lb[4];
#pragma unroll
    for (int r = 0; r < 4; ++r) lb[r] = __shfl(l, (lane & 48) | (lg * 4 + r));
#pragma unroll
    for (int r = 0; r < 4; ++r) {
      float inv = 1.f / lb[r];
      int q = q0w + lg * 4 + r;
      u16* orow = Ao + ((size_t)(b * 2048 + q)) * 1024 + h * 64 + lr;
#pragma unroll
      for (int d4 = 0; d4 < 4; ++d4) orow[d4 * 16] = f2b(oacc[d4][r] * inv);
    }
  }
}

// ---------------- output projection: 128x128 tile, BK=32, 3-slot counted ring, f32 out ----------------
__global__ __launch_bounds__(256, 3) void gemm_wo_k(const u16* __restrict__ Ab,
                                                    const u16* __restrict__ Wo,
                                                    float* __restrict__ Out) {
  __shared__ u16 As[3][4096];
  __shared__ u16 Bs[3][4096];
  const int wgid = blockIdx.x;
  const int xcd = wgid & 7;
  const int idx = wgid >> 3;             // 0..63
  const int mt = xcd * 8 + (idx >> 3);   // 0..63
  const int nt = idx & 7;
  const int t = threadIdx.x;
  const int wave = t >> 6, lane = t & 63;
  const int lr = lane & 15, lg = lane >> 4;
  const int wr = wave >> 1, wc = wave & 1;

  const int rr0 = t >> 3;
  const int s8 = t & 7;
  const int sl8 = s8 ^ (rr0 & 7);
  const int js = sl8 >> 2;
  const int kcs = sl8 & 3;
  const u16* aS = Ab + (size_t)(mt * 128 + rr0 + 64 * js) * 1024 + kcs * 8;
  const u16* bS = Wo + (size_t)(nt * 128 + rr0 + 64 * js) * 1024 + kcs * 8;

  f32x4 acc[4][4];
#pragma unroll
  for (int i = 0; i < 4; ++i)
#pragma unroll
    for (int j = 0; j < 4; ++j) acc[i][j] = (f32x4){0.f, 0.f, 0.f, 0.f};

#pragma unroll
  for (int tt = 0; tt < 2; ++tt) {
    const int kcol = tt * 32;
    glds16(aS + kcol, &As[tt][t * 8]);
    glds16(aS + 32 * 1024 + kcol, &As[tt][2048 + t * 8]);
    glds16(bS + kcol, &Bs[tt][t * 8]);
    glds16(bS + 32 * 1024 + kcol, &Bs[tt][2048 + t * 8]);
  }
  asm volatile("s_waitcnt vmcnt(4)" ::: "memory");
  __builtin_amdgcn_s_barrier();

  const int arb = lr * 64 + (((wr << 2) + lg) ^ (lr & 7)) * 8;
  const int brb = lr * 64 + (((wc << 2) + lg) ^ (lr & 7)) * 8;

  int sl = 0, sp2 = 2;
  for (int tau = 0; tau < 32; ++tau) {
    const u16* Asl = &As[sl][0];
    const u16* Bsl = &Bs[sl][0];
    bf16x8 af[4], bf[4];
#pragma unroll
    for (int mi = 0; mi < 4; ++mi) af[mi] = *(const bf16x8*)&Asl[arb + mi * 1024];
#pragma unroll
    for (int nj = 0; nj < 4; ++nj) bf[nj] = *(const bf16x8*)&Bsl[brb + nj * 1024];
    if (tau < 30) {
      u16* Ad = &As[sp2][0];
      u16* Bd = &Bs[sp2][0];
      const int kcol = (tau + 2) * 32;
      glds16(aS + kcol, &Ad[t * 8]);
      glds16(aS + 32 * 1024 + kcol, &Ad[2048 + t * 8]);
      glds16(bS + kcol, &Bd[t * 8]);
      glds16(bS + 32 * 1024 + kcol, &Bd[2048 + t * 8]);
    }
#pragma unroll
    for (int mi = 0; mi < 4; ++mi)
#pragma unroll
      for (int nj = 0; nj < 4; ++nj)
        acc[mi][nj] = MFMA16(af[mi], bf[nj], acc[mi][nj]);
    if (tau < 30) asm volatile("s_waitcnt vmcnt(4)" ::: "memory");
    else asm volatile("s_waitcnt vmcnt(0)" ::: "memory");
    __builtin_amdgcn_s_barrier();
    sl = (sl == 2) ? 0 : sl + 1;
    sp2 = (sp2 == 2) ? 0 : sp2 + 1;
  }

  const int rbase = mt * 128 + wr * 64 + lg * 4;
  const int cbase = nt * 128 + wc * 64 + lr;
#pragma unroll
  for (int mi = 0; mi < 4; ++mi)
#pragma unroll
    for (int nj = 0; nj < 4; ++nj) {
      int row0 = rbase + mi * 16;
      int col = cbase + nj * 16;
#pragma unroll
      for (int r = 0; r < 4; ++r)
        Out[(size_t)(row0 + r) * 1024 + col] = acc[mi][nj][r];
    }
}

extern "C" void kernel_launch(void* const* d_in, const int* in_sizes, int n_in,
                              void* d_out, int out_size, void* d_ws, size_t ws_size,
                              hipStream_t stream) {
  const float* x = (const float*)d_in[0];
  const int* pos = (const int*)d_in[1];
  const float* wq = (const float*)d_in[2];
  const float* wk = (const float*)d_in[3];
  const float* wv = (const float*)d_in[4];
  const float* wo = (const float*)d_in[5];

  char* ws = (char*)d_ws;
  u16* xb = (u16*)ws;
  u16* wqb = xb + 8388608;
  u16* wkb = wqb + 1048576;
  u16* wvb = wkb + 1048576;
  u16* wob = wvb + 1048576;
  float2* tab = (float2*)(ws + 25165824);
  u16* Qp = (u16*)(ws + 27262976);
  u16* Kp = (u16*)(ws + 27262976 + 16777216);
  u16* Vt = (u16*)(ws + 27262976 + 2 * 16777216);
  u16* Ao = (u16*)(ws + 27262976 + 3 * 16777216);

  hipLaunchKernelGGL(cvt_k, dim3(12288), dim3(256), 0, stream, x, wq, wk, wv, wo, pos,
                     xb, tab);
  hipLaunchKernelGGL(gemm_qkv_k, dim3(1536), dim3(256), 0, stream, xb, wqb, wkb, wvb,
                     tab, Qp, Kp, Vt);
  hipLaunchKernelGGL(fattn_k, dim3(1024), dim3(512), 0, stream, Qp, Kp, Vt, Ao);
  hipLaunchKernelGGL(gemm_wo_k, dim3(512), dim3(256), 0, stream, Ao, wob, (float*)d_out);
}

// Round 17
// 160.822 us; speedup vs baseline: 1.0772x; 1.0067x over previous
//
#include <hip/hip_runtime.h>

typedef __bf16 bf16x8 __attribute__((ext_vector_type(8)));
typedef __bf16 bf16x2 __attribute__((ext_vector_type(2)));
typedef float f32x4 __attribute__((ext_vector_type(4)));
typedef float f32x2 __attribute__((ext_vector_type(2)));
typedef unsigned short u16;
typedef unsigned int u32;

#define MFMA16(a, b, c) __builtin_amdgcn_mfma_f32_16x16x32_bf16((a), (b), (c), 0, 0, 0)

__device__ __forceinline__ u16 f2b(float f) {
  u32 u = __float_as_uint(f);
  u += 0x7FFFu + ((u >> 16) & 1u);
  return (u16)(u >> 16);
}
__device__ __forceinline__ float b2f(u16 h) { return __uint_as_float(((u32)h) << 16); }

__device__ __forceinline__ u32 pkbf(float a, float b) {
  bf16x2 h = {(__bf16)a, (__bf16)b};  // v_cvt_pk_bf16_f32
  return __builtin_bit_cast(u32, h);
}

__device__ __forceinline__ float max3f(float a, float b, float c) {
  float d;
  asm("v_max3_f32 %0, %1, %2, %3" : "=v"(d) : "v"(a), "v"(b), "v"(c));
  return d;
}

__device__ __forceinline__ float exp2_(float x) {
#if __has_builtin(__builtin_amdgcn_exp2f)
  return __builtin_amdgcn_exp2f(x);
#else
  return exp2f(x);
#endif
}

__device__ __forceinline__ void glds16(const void* g, void* l) {
  __builtin_amdgcn_global_load_lds((const __attribute__((address_space(1))) void*)g,
                                   (__attribute__((address_space(3))) void*)l, 16, 0, 0);
}

// ---------------- f32 -> bf16 conversion + RoPE table (fused) ----------------
__global__ __launch_bounds__(256) void cvt_k(const float* __restrict__ x,
                                             const float* __restrict__ wq,
                                             const float* __restrict__ wk,
                                             const float* __restrict__ wv,
                                             const float* __restrict__ wo,
                                             const int* __restrict__ pos,
                                             u16* __restrict__ dst,
                                             float2* __restrict__ tab) {
  size_t e = ((size_t)blockIdx.x * 256 + threadIdx.x) * 4;
  const float* src;
  size_t off;
  if (e < 8388608ull) {
    src = x; off = e;
  } else {
    size_t r = e - 8388608ull;
    u32 wi = (u32)(r >> 20);
    off = r & 1048575ull;
    src = (wi == 0) ? wq : (wi == 1) ? wk : (wi == 2) ? wv : wo;
  }
  float4 v = *(const float4*)(src + off);
  ushort4 o = make_ushort4(f2b(v.x), f2b(v.y), f2b(v.z), f2b(v.w));
  *(ushort4*)(dst + e) = o;
  if (blockIdx.x < 1024) {
    int i = blockIdx.x * 256 + threadIdx.x;
    int row = i >> 5, j = i & 31;
    float p = (float)pos[row];
    float inv = exp2f((float)j * -0.41524101186092029f);  // 10000^(-j/32)
    float s, c;
    sincosf(p * inv, &s, &c);
    tab[i] = make_float2(c, s);
  }
}

// ---------------- QKV projection GEMM: 128x128 tile, BK=32, 3-slot counted ring ----------------
// R13/R14-best: 48KB LDS -> 3 blocks/CU; 1536 blocks = 2 perfect rounds; pin-less K-loop.
__global__ __launch_bounds__(256, 3) void gemm_qkv_k(const u16* __restrict__ Xb,
                                                     const u16* __restrict__ Wq,
                                                     const u16* __restrict__ Wk,
                                                     const u16* __restrict__ Wv,
                                                     const float2* __restrict__ tab,
                                                     u16* __restrict__ Qp,
                                                     u16* __restrict__ Kp,
                                                     u16* __restrict__ Vt) {
  __shared__ u16 As[3][4096];  // 8KB per slot
  __shared__ u16 Bs[3][4096];
  const int wgid = blockIdx.x;
  const int xcd = wgid & 7;
  const int idx = wgid >> 3;              // 0..191
  const int P = xcd * 24 + (idx >> 3);    // 0..191 panels (z-major)
  const int nt = idx & 7;
  const int z = P >> 6;
  const int mt = P & 63;
  const u16* W = (z == 0) ? Wq : (z == 1) ? Wk : Wv;
  const int t = threadIdx.x;
  const int wave = t >> 6, lane = t & 63;
  const int lr = lane & 15, lg = lane >> 4;
  const int wr = wave >> 1, wc = wave & 1;  // 2x2 wave grid, wave-tile 64x64

  const int rr0 = t >> 3;                 // 0..31
  const int s8 = t & 7;
  const int sl8 = s8 ^ (rr0 & 7);
  const int js = sl8 >> 2;                // row-half
  const int kcs = sl8 & 3;                // k-chunk
  const u16* aS = Xb + (size_t)(mt * 128 + rr0 + 64 * js) * 1024 + kcs * 8;
  const u16* bS = W + (size_t)(nt * 128 + rr0 + 64 * js) * 1024 + kcs * 8;

  f32x4 acc[4][4];
#pragma unroll
  for (int i = 0; i < 4; ++i)
#pragma unroll
    for (int j = 0; j < 4; ++j) acc[i][j] = (f32x4){0.f, 0.f, 0.f, 0.f};

#pragma unroll
  for (int tt = 0; tt < 2; ++tt) {
    const int kcol = tt * 32;
    glds16(aS + kcol, &As[tt][t * 8]);
    glds16(aS + 32 * 1024 + kcol, &As[tt][2048 + t * 8]);
    glds16(bS + kcol, &Bs[tt][t * 8]);
    glds16(bS + 32 * 1024 + kcol, &Bs[tt][2048 + t * 8]);
  }
  asm volatile("s_waitcnt vmcnt(4)" ::: "memory");
  __builtin_amdgcn_s_barrier();

  const int arb = lr * 64 + (((wr << 2) + lg) ^ (lr & 7)) * 8;
  const int brb = lr * 64 + (((wc << 2) + lg) ^ (lr & 7)) * 8;

  int sl = 0, sp2 = 2;
  for (int tau = 0; tau < 32; ++tau) {
    const u16* Asl = &As[sl][0];
    const u16* Bsl = &Bs[sl][0];
    bf16x8 af[4], bf[4];
#pragma unroll
    for (int mi = 0; mi < 4; ++mi) af[mi] = *(const bf16x8*)&Asl[arb + mi * 1024];
#pragma unroll
    for (int nj = 0; nj < 4; ++nj) bf[nj] = *(const bf16x8*)&Bsl[brb + nj * 1024];
    if (tau < 30) {
      u16* Ad = &As[sp2][0];
      u16* Bd = &Bs[sp2][0];
      const int kcol = (tau + 2) * 32;
      glds16(aS + kcol, &Ad[t * 8]);
      glds16(aS + 32 * 1024 + kcol, &Ad[2048 + t * 8]);
      glds16(bS + kcol, &Bd[t * 8]);
      glds16(bS + 32 * 1024 + kcol, &Bd[2048 + t * 8]);
    }
    // compiler-scheduled ds_read->MFMA interleave; reads retire before end barrier.
#pragma unroll
    for (int mi = 0; mi < 4; ++mi)
#pragma unroll
      for (int nj = 0; nj < 4; ++nj)
        acc[mi][nj] = MFMA16(af[mi], bf[nj], acc[mi][nj]);
    if (tau < 30) asm volatile("s_waitcnt vmcnt(4)" ::: "memory");
    else asm volatile("s_waitcnt vmcnt(0)" ::: "memory");
    __builtin_amdgcn_s_barrier();
    sl = (sl == 2) ? 0 : sl + 1;
    sp2 = (sp2 == 2) ? 0 : sp2 + 1;
  }

  const int rbase = mt * 128 + wr * 64 + lg * 4;
  const int cbase = nt * 128 + wc * 64 + lr;
  if (z < 2) {
    u16* out = (z == 0) ? Qp : Kp;
    const float scl = (z == 0) ? 0.18033688011112043f : 1.0f;  // 0.125*log2(e) for Q
#pragma unroll
    for (int mi = 0; mi < 4; ++mi)
#pragma unroll
      for (int nj = 0; nj < 4; ++nj) {
        int row0 = rbase + mi * 16;
        int col = cbase + nj * 16;
        int j = (col >> 1) & 31;
        float sgn = (col & 1) ? 1.f : -1.f;
#pragma unroll
        for (int r = 0; r < 4; ++r) {
          float self = acc[mi][nj][r];
          float partner = __shfl_xor(self, 1);
          float2 cs = tab[(size_t)(row0 + r) * 32 + j];
          float o = (self * cs.x + partner * cs.y * sgn) * scl;
          out[(size_t)(row0 + r) * 1024 + col] = f2b(o);
        }
      }
  } else {
#pragma unroll
    for (int mi = 0; mi < 4; ++mi)
#pragma unroll
      for (int nj = 0; nj < 4; ++nj) {
        int row0 = rbase + mi * 16;
        int e = cbase + nj * 16;
        int b = row0 >> 11, s = row0 & 2047;
        ushort4 pk = make_ushort4(f2b(acc[mi][nj][0]), f2b(acc[mi][nj][1]),
                                  f2b(acc[mi][nj][2]), f2b(acc[mi][nj][3]));
        *(ushort4*)&Vt[((size_t)(b * 1024 + e)) * 2048 + s] = pk;
      }
  }
}

// ---------------- causal flash attention: 8 waves x 16 q-rows, 128 q/block, 1024 blocks ----------------
// + T5 setprio around MFMA clusters (cross-block wave phase diversity, 3 blocks/CU).
__global__ __launch_bounds__(512, 6) void fattn_k(const u16* __restrict__ Qp,
                                                  const u16* __restrict__ Kp,
                                                  const u16* __restrict__ Vt,
                                                  u16* __restrict__ Ao) {
  __shared__ u16 Ks[2][64 * 64];    // [buf][kv][d], swizzled (16KB)
  __shared__ u16 Vs[2][64 * 64];    // [buf][d][kv], swizzled (16KB)
  __shared__ u16 Ps[8][16 * 64];    // per-wave [q16][kv64], swizzled (16KB)
  const int blk = blockIdx.x;
  const int g = blk & 7, jj = blk >> 3;     // 1024 blocks, jj 0..127
  const int bh = g * 8 + (jj & 7);          // xcd g owns bh [8g, 8g+8)
  const int qt = 15 - (jj >> 3);            // long blocks first (qt 15..0)
  const int b = bh >> 4, h = bh & 15;
  const int tid = threadIdx.x, wave = tid >> 6, lane = tid & 63;
  const int lr = lane & 15, lg = lane >> 4;
  const int q0w = qt * 128 + wave * 16;

  bf16x8 qf0, qf1;
  {
    const u16* qb = Qp + ((size_t)(b * 2048 + q0w + lr)) * 1024 + h * 64 + lg * 8;
    qf0 = *(const bf16x8*)qb;
    qf1 = *(const bf16x8*)(qb + 32);
  }

  float m = -1e30f, l = 0.f;
  f32x4 oacc[4];
#pragma unroll
  for (int d4 = 0; d4 < 4; ++d4) oacc[d4] = (f32x4){0.f, 0.f, 0.f, 0.f};
  const f32x4 fz = {0.f, 0.f, 0.f, 0.f};

  const int srow = lane >> 3;
  const int schunk = (lane & 7) ^ srow;
  const u16* kbase = Kp + ((size_t)(b * 2048 + 8 * wave + srow)) * 1024 + h * 64 + schunk * 8;
  const u16* vbase = Vt + ((size_t)(b * 1024 + h * 64 + 8 * wave + srow)) * 2048 + schunk * 8;
  char* psbase = (char*)&Ps[wave][0];

  const int ktmax = 2 * qt + 1;
  const int ktneed = 2 * qt + (wave >> 2);

  glds16(kbase, &Ks[0][(8 * wave) * 64]);
  glds16(vbase, &Vs[0][(8 * wave) * 64]);

  int cur = 0;
  for (int kt = 0; kt <= ktmax; ++kt, cur ^= 1) {
    __syncthreads();
    if (kt < ktmax) {
      const int nx = cur ^ 1, k1 = kt + 1;
      glds16(kbase + (size_t)k1 * 65536, &Ks[nx][(8 * wave) * 64]);
      glds16(vbase + k1 * 64, &Vs[nx][(8 * wave) * 64]);
    }
    if (kt > ktneed) continue;
    const u16* KB = &Ks[cur][0];
    const u16* VB = &Vs[cur][0];

    f32x4 sc[4];
    __builtin_amdgcn_s_setprio(1);
#pragma unroll
    for (int ks = 0; ks < 4; ++ks) {
      const int krow = ks * 16 + lr;
      const int swk = lr & 7;
      bf16x8 kf0 = *(const bf16x8*)&KB[krow * 64 + ((lg ^ swk) * 8)];
      bf16x8 kf1 = *(const bf16x8*)&KB[krow * 64 + (((lg + 4) ^ swk) * 8)];
      f32x4 s = MFMA16(kf0, qf0, fz);
      s = MFMA16(kf1, qf1, s);
      sc[ks] = s;
    }
    __builtin_amdgcn_s_setprio(0);
    if (kt == ktneed) {  // causal mask (diagonal tile only)
      int q = q0w + lr;
#pragma unroll
      for (int ks = 0; ks < 4; ++ks)
#pragma unroll
        for (int r = 0; r < 4; ++r) {
          int kv = kt * 64 + ks * 16 + lg * 4 + r;
          if (kv > q) sc[ks][r] = -__builtin_inff();
        }
    }

    {
      float t0 = max3f(sc[0][0], sc[0][1], sc[0][2]);
      float t1 = max3f(sc[0][3], sc[1][0], sc[1][1]);
      float t2 = max3f(sc[1][2], sc[1][3], sc[2][0]);
      float t3 = max3f(sc[2][1], sc[2][2], sc[2][3]);
      float t4 = max3f(sc[3][0], sc[3][1], sc[3][2]);
      float pm = max3f(max3f(t0, t1, t2), max3f(t3, t4, sc[3][3]), -1e30f);
      pm = fmaxf(pm, __shfl_xor(pm, 16));
      pm = fmaxf(pm, __shfl_xor(pm, 32));
      if (__any(pm > m + 8.f)) {
        float mn = fmaxf(m, pm);
        float corr = exp2_(m - mn);
        m = mn;
        l *= corr;
        float cb[4];
#pragma unroll
        for (int r = 0; r < 4; ++r) cb[r] = __shfl(corr, (lane & 48) | (lg * 4 + r));
#pragma unroll
        for (int d4 = 0; d4 < 4; ++d4)
#pragma unroll
          for (int r = 0; r < 4; ++r) oacc[d4][r] *= cb[r];
      }
      const f32x2 ms = {m, m};
      f32x2 rs2 = {0.f, 0.f};
#pragma unroll
      for (int ks = 0; ks < 4; ++ks) {
        f32x2 lo = {sc[ks][0], sc[ks][1]};
        f32x2 hi = {sc[ks][2], sc[ks][3]};
        lo = lo - ms;
        hi = hi - ms;
        lo[0] = exp2_(lo[0]); lo[1] = exp2_(lo[1]);
        hi[0] = exp2_(hi[0]); hi[1] = exp2_(hi[1]);
        rs2 += lo;
        rs2 += hi;
        sc[ks][0] = lo[0]; sc[ks][1] = lo[1];
        sc[ks][2] = hi[0]; sc[ks][3] = hi[1];
      }
      float rs = rs2[0] + rs2[1];
      rs += __shfl_xor(rs, 16);
      rs += __shfl_xor(rs, 32);
      l += rs;
    }

    bf16x8 pa0, pa1;
    {
      const int swp = lr & 7;
#pragma unroll
      for (int ks = 0; ks < 4; ++ks) {
        const int chunk = (2 * ks + (lg >> 1)) ^ swp;
        char* p = psbase + lr * 128 + chunk * 16 + (lg & 1) * 8;
        *(uint2*)p = make_uint2(pkbf(sc[ks][0], sc[ks][1]),
                                pkbf(sc[ks][2], sc[ks][3]));
      }
      pa0 = *(const bf16x8*)(psbase + lr * 128 + ((lg ^ swp) * 16));
      pa1 = *(const bf16x8*)(psbase + lr * 128 + (((lg + 4) ^ swp) * 16));
    }
    __builtin_amdgcn_s_setprio(1);
#pragma unroll
    for (int d4 = 0; d4 < 4; ++d4) {
      const int vrow = d4 * 16 + lr;
      const int swv = lr & 7;
      bf16x8 vf0 = *(const bf16x8*)&VB[vrow * 64 + ((lg ^ swv) * 8)];
      bf16x8 vf1 = *(const bf16x8*)&VB[vrow * 64 + (((lg + 4) ^ swv) * 8)];
      oacc[d4] = MFMA16(pa0, vf0, oacc[d4]);
      oacc[d4] = MFMA16(pa1, vf1, oacc[d4]);
    }
    __builtin_amdgcn_s_setprio(0);
  }

  {
    float lb[4];
#pragma unroll
    for (int r = 0; r < 4; ++r) lb[r] = __shfl(l, (lane & 48) | (lg * 4 + r));
#pragma unroll
    for (int r = 0; r < 4; ++r) {
      float inv = 1.f / lb[r];
      int q = q0w + lg * 4 + r;
      u16* orow = Ao + ((size_t)(b * 2048 + q)) * 1024 + h * 64 + lr;
#pragma unroll
      for (int d4 = 0; d4 < 4; ++d4) orow[d4 * 16] = f2b(oacc[d4][r] * inv);
    }
  }
}

// ---------------- output projection: 128x128 tile, BK=32, 3-slot counted ring, f32 out ----------------
__global__ __launch_bounds__(256, 3) void gemm_wo_k(const u16* __restrict__ Ab,
                                                    const u16* __restrict__ Wo,
                                                    float* __restrict__ Out) {
  __shared__ u16 As[3][4096];
  __shared__ u16 Bs[3][4096];
  const int wgid = blockIdx.x;
  const int xcd = wgid & 7;
  const int idx = wgid >> 3;             // 0..63
  const int mt = xcd * 8 + (idx >> 3);   // 0..63
  const int nt = idx & 7;
  const int t = threadIdx.x;
  const int wave = t >> 6, lane = t & 63;
  const int lr = lane & 15, lg = lane >> 4;
  const int wr = wave >> 1, wc = wave & 1;

  const int rr0 = t >> 3;
  const int s8 = t & 7;
  const int sl8 = s8 ^ (rr0 & 7);
  const int js = sl8 >> 2;
  const int kcs = sl8 & 3;
  const u16* aS = Ab + (size_t)(mt * 128 + rr0 + 64 * js) * 1024 + kcs * 8;
  const u16* bS = Wo + (size_t)(nt * 128 + rr0 + 64 * js) * 1024 + kcs * 8;

  f32x4 acc[4][4];
#pragma unroll
  for (int i = 0; i < 4; ++i)
#pragma unroll
    for (int j = 0; j < 4; ++j) acc[i][j] = (f32x4){0.f, 0.f, 0.f, 0.f};

#pragma unroll
  for (int tt = 0; tt < 2; ++tt) {
    const int kcol = tt * 32;
    glds16(aS + kcol, &As[tt][t * 8]);
    glds16(aS + 32 * 1024 + kcol, &As[tt][2048 + t * 8]);
    glds16(bS + kcol, &Bs[tt][t * 8]);
    glds16(bS + 32 * 1024 + kcol, &Bs[tt][2048 + t * 8]);
  }
  asm volatile("s_waitcnt vmcnt(4)" ::: "memory");
  __builtin_amdgcn_s_barrier();

  const int arb = lr * 64 + (((wr << 2) + lg) ^ (lr & 7)) * 8;
  const int brb = lr * 64 + (((wc << 2) + lg) ^ (lr & 7)) * 8;

  int sl = 0, sp2 = 2;
  for (int tau = 0; tau < 32; ++tau) {
    const u16* Asl = &As[sl][0];
    const u16* Bsl = &Bs[sl][0];
    bf16x8 af[4], bf[4];
#pragma unroll
    for (int mi = 0; mi < 4; ++mi) af[mi] = *(const bf16x8*)&Asl[arb + mi * 1024];
#pragma unroll
    for (int nj = 0; nj < 4; ++nj) bf[nj] = *(const bf16x8*)&Bsl[brb + nj * 1024];
    if (tau < 30) {
      u16* Ad = &As[sp2][0];
      u16* Bd = &Bs[sp2][0];
      const int kcol = (tau + 2) * 32;
      glds16(aS + kcol, &Ad[t * 8]);
      glds16(aS + 32 * 1024 + kcol, &Ad[2048 + t * 8]);
      glds16(bS + kcol, &Bd[t * 8]);
      glds16(bS + 32 * 1024 + kcol, &Bd[2048 + t * 8]);
    }
#pragma unroll
    for (int mi = 0; mi < 4; ++mi)
#pragma unroll
      for (int nj = 0; nj < 4; ++nj)
        acc[mi][nj] = MFMA16(af[mi], bf[nj], acc[mi][nj]);
    if (tau < 30) asm volatile("s_waitcnt vmcnt(4)" ::: "memory");
    else asm volatile("s_waitcnt vmcnt(0)" ::: "memory");
    __builtin_amdgcn_s_barrier();
    sl = (sl == 2) ? 0 : sl + 1;
    sp2 = (sp2 == 2) ? 0 : sp2 + 1;
  }

  const int rbase = mt * 128 + wr * 64 + lg * 4;
  const int cbase = nt * 128 + wc * 64 + lr;
#pragma unroll
  for (int mi = 0; mi < 4; ++mi)
#pragma unroll
    for (int nj = 0; nj < 4; ++nj) {
      int row0 = rbase + mi * 16;
      int col = cbase + nj * 16;
#pragma unroll
      for (int r = 0; r < 4; ++r)
        Out[(size_t)(row0 + r) * 1024 + col] = acc[mi][nj][r];
    }
}

extern "C" void kernel_launch(void* const* d_in, const int* in_sizes, int n_in,
                              void* d_out, int out_size, void* d_ws, size_t ws_size,
                              hipStream_t stream) {
  const float* x = (const float*)d_in[0];
  const int* pos = (const int*)d_in[1];
  const float* wq = (const float*)d_in[2];
  const float* wk = (const float*)d_in[3];
  const float* wv = (const float*)d_in[4];
  const float* wo = (const float*)d_in[5];

  char* ws = (char*)d_ws;
  u16* xb = (u16*)ws;
  u16* wqb = xb + 8388608;
  u16* wkb = wqb + 1048576;
  u16* wvb = wkb + 1048576;
  u16* wob = wvb + 1048576;
  float2* tab = (float2*)(ws + 25165824);
  u16* Qp = (u16*)(ws + 27262976);
  u16* Kp = (u16*)(ws + 27262976 + 16777216);
  u16* Vt = (u16*)(ws + 27262976 + 2 * 16777216);
  u16* Ao = (u16*)(ws + 27262976 + 3 * 16777216);

  hipLaunchKernelGGL(cvt_k, dim3(12288), dim3(256), 0, stream, x, wq, wk, wv, wo, pos,
                     xb, tab);
  hipLaunchKernelGGL(gemm_qkv_k, dim3(1536), dim3(256), 0, stream, xb, wqb, wkb, wvb,
                     tab, Qp, Kp, Vt);
  hipLaunchKernelGGL(fattn_k, dim3(1024), dim3(512), 0, stream, Qp, Kp, Vt, Ao);
  hipLaunchKernelGGL(gemm_wo_k, dim3(512), dim3(256), 0, stream, Ao, wob, (float*)d_out);
}